// Round 7
// baseline (285.617 us; speedup 1.0000x reference)
//
#include <hip/hip_runtime.h>

// HGNN aggregation: out = x + segment_sum(x[src_idx], dst_idx)
// x: [100000, 128] f32; src_idx/dst_idx: [2,000,000] int32.
//
// Round 7: single-pass slotted partition.
//   1. memset cursors (+ spill counter)
//   2. convert+partition: x -> bf16 mirror AND src scattered into
//      fixed-stride per-node slot windows (degree ~ Poisson(20), slot
//      adaptively 30..64; overflow -> spill list)
//   3. aggregate: one wave per node, 32 lanes x ushort4 bf16 gather,
//      2 edges per wave-instr / 8 in flight, f32 accum + exact f32 residual
//   4. spill_apply: f32 atomic add for spilled edges (expected ~0)

constexpr int DIM = 128;

__device__ inline unsigned short f2bf(float f) {
    unsigned u = __float_as_uint(f);
    u = (u + 0x7FFFu + ((u >> 16) & 1u)) >> 16;   // RTNE
    return (unsigned short)u;
}
__device__ inline float bf2f(unsigned short h) {
    return __uint_as_float((unsigned)h << 16);
}

__global__ void hgnn_convert_partition(const float4* __restrict__ x4,
                                       ushort4* __restrict__ xh4, int n4,
                                       const int* __restrict__ src,
                                       const int* __restrict__ dst,
                                       int* __restrict__ cursor,
                                       int* __restrict__ part, int slot,
                                       int* __restrict__ spillCnt,
                                       int2* __restrict__ spill, int spillCap,
                                       int nedges) {
    int i = blockIdx.x * blockDim.x + threadIdx.x;
    int stride = gridDim.x * blockDim.x;
    // x -> bf16 mirror
    for (int k = i; k < n4; k += stride) {
        float4 v = x4[k];
        ushort4 o;
        o.x = f2bf(v.x); o.y = f2bf(v.y);
        o.z = f2bf(v.z); o.w = f2bf(v.w);
        xh4[k] = o;
    }
    // scatter src ids into per-dst slot windows
    for (int k = i; k < nedges; k += stride) {
        int s = src[k];
        int d = dst[k];
        int pos = atomicAdd(&cursor[d], 1);
        if (pos < slot) {
            part[(size_t)d * slot + pos] = s;
        } else {
            int sp = atomicAdd(spillCnt, 1);
            if (sp < spillCap) spill[sp] = make_int2(s, d);
        }
    }
}

// one wave per node; 32 lanes own the row (ushort4 each); halves h=0/1
// process even/odd slot entries; shfl_xor(32) combines.
__global__ void hgnn_aggregate_bf16(const float4* __restrict__ x4,
                                    const ushort4* __restrict__ xh4,
                                    const int* __restrict__ part, int slot,
                                    const int* __restrict__ cursor,
                                    float4* __restrict__ out4, int nnodes) {
    int gtid = blockIdx.x * blockDim.x + threadIdx.x;
    int node = gtid >> 6;
    if (node >= nnodes) return;
    int lane = threadIdx.x & 63;
    int h = lane >> 5;
    int c = lane & 31;

    int cnt = cursor[node];
    if (cnt > slot) cnt = slot;
    const int* pp = part + (size_t)node * slot;

    float4 acc = make_float4(0.f, 0.f, 0.f, 0.f);
    int j = 0;
    for (; j + 8 <= cnt; j += 8) {
        int s0 = pp[j + h];
        int s1 = pp[j + 2 + h];
        int s2 = pp[j + 4 + h];
        int s3 = pp[j + 6 + h];
        ushort4 v0 = xh4[(size_t)s0 * 32 + c];
        ushort4 v1 = xh4[(size_t)s1 * 32 + c];
        ushort4 v2 = xh4[(size_t)s2 * 32 + c];
        ushort4 v3 = xh4[(size_t)s3 * 32 + c];
        acc.x += (bf2f(v0.x) + bf2f(v1.x)) + (bf2f(v2.x) + bf2f(v3.x));
        acc.y += (bf2f(v0.y) + bf2f(v1.y)) + (bf2f(v2.y) + bf2f(v3.y));
        acc.z += (bf2f(v0.z) + bf2f(v1.z)) + (bf2f(v2.z) + bf2f(v3.z));
        acc.w += (bf2f(v0.w) + bf2f(v1.w)) + (bf2f(v2.w) + bf2f(v3.w));
    }
    for (; j < cnt; j += 2) {
        int e = j + h;
        if (e < cnt) {
            int p = pp[e];
            ushort4 v = xh4[(size_t)p * 32 + c];
            acc.x += bf2f(v.x);
            acc.y += bf2f(v.y);
            acc.z += bf2f(v.z);
            acc.w += bf2f(v.w);
        }
    }

    acc.x += __shfl_xor(acc.x, 32);
    acc.y += __shfl_xor(acc.y, 32);
    acc.z += __shfl_xor(acc.z, 32);
    acc.w += __shfl_xor(acc.w, 32);

    if (h == 0) {
        float4 xv = x4[(size_t)node * 32 + c];   // exact f32 residual
        out4[(size_t)node * 32 + c] =
            make_float4(xv.x + acc.x, xv.y + acc.y, xv.z + acc.z, xv.w + acc.w);
    }
}

// handles slot-overflow edges (expected none on this data)
__global__ void hgnn_spill_apply(const float4* __restrict__ x4,
                                 const int* __restrict__ spillCnt,
                                 const int2* __restrict__ spill,
                                 float* __restrict__ out, int spillCap) {
    int n = *spillCnt;
    if (n > spillCap) n = spillCap;
    int i = blockIdx.x * blockDim.x + threadIdx.x;
    int stride = gridDim.x * blockDim.x;
    for (int k = i; k < n * 32; k += stride) {
        int e = k >> 5;
        int c = k & 31;
        int2 sd = spill[e];
        float4 v = x4[(size_t)sd.x * 32 + c];
        float* o = out + (size_t)sd.y * DIM + c * 4;
        atomicAdd(o + 0, v.x);
        atomicAdd(o + 1, v.y);
        atomicAdd(o + 2, v.z);
        atomicAdd(o + 3, v.w);
    }
}

static inline size_t align256(size_t v) { return (v + 255) & ~(size_t)255; }

extern "C" void kernel_launch(void* const* d_in, const int* in_sizes, int n_in,
                              void* d_out, int out_size, void* d_ws, size_t ws_size,
                              hipStream_t stream) {
    const float* x = (const float*)d_in[0];
    const int* src = (const int*)d_in[1];
    const int* dst = (const int*)d_in[2];
    float* out = (float*)d_out;

    const int E = in_sizes[1];            // 2,000,000
    const int N = in_sizes[0] / DIM;      // 100,000
    const int n4 = N * (DIM / 4);         // 3.2M float4

    // workspace layout: cursor[N] + spillCnt | xh bf16 mirror | part | spill
    char* w = (char*)d_ws;
    size_t curBytes = align256((size_t)(N + 1) * sizeof(int));
    size_t xhBytes = align256((size_t)N * DIM * 2);        // 25.6 MB
    size_t fixedBytes = curBytes + xhBytes;
    size_t spillReserve = 256 * 1024;                      // >= 16K spill entries

    size_t rem = (ws_size > fixedBytes + spillReserve)
                     ? (ws_size - fixedBytes - spillReserve) : 0;
    int slot = (int)((rem / sizeof(int)) / (size_t)N);
    if (slot > 64) slot = 64;
    if (slot < 4) slot = 4;               // degenerate ws; spill net still correct

    int* cursor = (int*)w;                               // [N]
    int* spillCnt = cursor + N;                          // [1]
    ushort* xh = (ushort*)(w + curBytes);                // [N*128] bf16
    int* part = (int*)(w + fixedBytes);                  // [N*slot]
    size_t partBytes = align256((size_t)N * slot * sizeof(int));
    int2* spill = (int2*)(w + fixedBytes + partBytes);
    int spillCap = (int)((ws_size > fixedBytes + partBytes)
                             ? (ws_size - fixedBytes - partBytes) / sizeof(int2) : 0);

    // 1) zero cursors + spill counter
    hipMemsetAsync(cursor, 0, (size_t)(N + 1) * sizeof(int), stream);

    // 2) convert + slotted partition
    hipLaunchKernelGGL(hgnn_convert_partition, dim3(2048), dim3(256), 0, stream,
                       (const float4*)x, (ushort4*)xh, n4,
                       src, dst, cursor, part, slot,
                       spillCnt, spill, spillCap, E);

    // 3) gather-aggregate
    {
        int grid = (N * 64 + 255) / 256;   // one wave per node
        hipLaunchKernelGGL(hgnn_aggregate_bf16, dim3(grid), dim3(256), 0, stream,
                           (const float4*)x, (const ushort4*)xh, part, slot,
                           cursor, (float4*)out, N);
    }

    // 4) apply spilled edges (normally zero work)
    hipLaunchKernelGGL(hgnn_spill_apply, dim3(64), dim3(256), 0, stream,
                       (const float4*)x, spillCnt, spill, out, spillCap);
}

// Round 8
// 152.637 us; speedup vs baseline: 1.8712x; 1.8712x over previous
//
#include <hip/hip_runtime.h>

// HGNN aggregation: out = x + segment_sum(x[src_idx], dst_idx)
// x: [100000, 128] f32; src_idx/dst_idx: [2,000,000] int32.
//
// Round 8: reservation-arena partition + fused sort/aggregate.
//   1. memset bucket cursors (+ spill counter)             (~2 us)
//   2. convert: x -> bf16 mirror                           (~15 us)
//   3. partition_arena: per-block LDS histogram over its 8K-edge chunk,
//      ONE global reservation per (block,bucket) -> clustered writes of
//      packed src|(dstLocal<<17) into per-bucket fixed arenas (CAP=3072,
//      mean 2558, +10 sigma; overflow -> spill list)       (~35 us)
//   4. aggregate_sorted: 4 blocks per bucket; each stages the bucket's
//      arena run, LDS counting-sort by node (2 global passes, parallel
//      scan), then 4 waves x 8 nodes gather bf16 rows 16-deep,
//      f32 accum + exact f32 residual                      (~110 us)
//   5. spill_apply: f32 atomics for overflow (expected 0)  (~3 us)

constexpr int DIM = 128;
constexpr int BSHIFT = 7;            // 128 nodes per bucket
constexpr int GNODES = 1 << BSHIFT;  // 128
constexpr int MAXB = 1024;           // max buckets (N <= 131072)
constexpr int CE = 8192;             // edges per partition block
constexpr int CAP_MAX = 3072;        // arena slots per bucket (LDS-sized)

__device__ inline unsigned short f2bf(float f) {
    unsigned u = __float_as_uint(f);
    u = (u + 0x7FFFu + ((u >> 16) & 1u)) >> 16;   // RTNE
    return (unsigned short)u;
}
__device__ inline float bf2f(unsigned short h) {
    return __uint_as_float((unsigned)h << 16);
}

__global__ void hgnn_convert(const float4* __restrict__ x4,
                             ushort4* __restrict__ xh4, int n4) {
    int i = blockIdx.x * blockDim.x + threadIdx.x;
    int stride = gridDim.x * blockDim.x;
    for (int k = i; k < n4; k += stride) {
        float4 v = x4[k];
        ushort4 o;
        o.x = f2bf(v.x); o.y = f2bf(v.y);
        o.z = f2bf(v.z); o.w = f2bf(v.w);
        xh4[k] = o;
    }
}

__global__ void hgnn_partition_arena(const int* __restrict__ src,
                                     const int* __restrict__ dst,
                                     int* __restrict__ cursor,
                                     int* __restrict__ arena, int cap,
                                     int* __restrict__ spillCnt,
                                     int2* __restrict__ spill, int spillCap,
                                     int nedges, int nbk) {
    __shared__ int h[MAXB];
    __shared__ int lb[MAXB];
    int c0 = blockIdx.x * CE;
    int c1 = min(c0 + CE, nedges);
    for (int i = threadIdx.x; i < nbk; i += blockDim.x) h[i] = 0;
    __syncthreads();
    for (int i = c0 + threadIdx.x; i < c1; i += blockDim.x)
        atomicAdd(&h[dst[i] >> BSHIFT], 1);
    __syncthreads();
    for (int i = threadIdx.x; i < nbk; i += blockDim.x)
        lb[i] = h[i] ? atomicAdd(&cursor[i], h[i]) : 0;
    __syncthreads();
    for (int i = c0 + threadIdx.x; i < c1; i += blockDim.x) {
        int s = src[i];
        int d = dst[i];
        int bk = d >> BSHIFT;
        int pos = atomicAdd(&lb[bk], 1);
        if (pos < cap) {
            arena[(size_t)bk * cap + pos] = s | ((d & (GNODES - 1)) << 17);
        } else {
            int sp = atomicAdd(spillCnt, 1);
            if (sp < spillCap) spill[sp] = make_int2(s, d);
        }
    }
}

// 4 blocks per bucket (q = blockIdx&3 -> nodes q*32..q*32+31).
// Two global passes over the bucket's arena run: (1) 128-bin LDS hist,
// (2) scatter into sorted LDS list. Then 4 waves x 8 nodes gather.
__global__ void hgnn_aggregate_sorted(const float4* __restrict__ x4,
                                      const ushort4* __restrict__ xh4,
                                      const int* __restrict__ arena, int cap,
                                      const int* __restrict__ cursor,
                                      float4* __restrict__ out4, int nnodes) {
    __shared__ int sorted[CAP_MAX];
    __shared__ int hoff[GNODES + 1];
    __shared__ int hcur[GNODES];

    const int b = blockIdx.x >> 2;
    const int q = blockIdx.x & 3;
    const int tid = threadIdx.x;
    const int wv = tid >> 6;
    const int lane = tid & 63;
    const int h = lane >> 5;
    const int c = lane & 31;

    int cnt = cursor[b];
    if (cnt > cap) cnt = cap;
    const int* ar = arena + (size_t)b * cap;

    // pass 1: histogram by local node id
    for (int i = tid; i < GNODES; i += blockDim.x) hcur[i] = 0;
    __syncthreads();
    for (int i = tid; i < cnt; i += blockDim.x)
        atomicAdd(&hcur[ar[i] >> 17], 1);
    __syncthreads();

    // parallel exclusive scan of 128 counts (Hillis-Steele, 2 waves)
    int myc = (tid < GNODES) ? hcur[tid] : 0;
    if (tid < GNODES) hoff[tid] = myc;
    __syncthreads();
    for (int off = 1; off < GNODES; off <<= 1) {
        int v = (tid < GNODES && tid >= off) ? hoff[tid - off] : 0;
        __syncthreads();
        if (tid < GNODES) hoff[tid] += v;
        __syncthreads();
    }
    if (tid < GNODES) {
        int excl = hoff[tid] - myc;     // convert inclusive -> exclusive
        hcur[tid] = excl;
        if (tid == GNODES - 1) hoff[GNODES] = excl + myc;  // == cnt
    }
    __syncthreads();
    if (tid < GNODES) hoff[tid] = hcur[tid];
    __syncthreads();

    // pass 2: scatter into sorted list (keeps packed word)
    for (int i = tid; i < cnt; i += blockDim.x) {
        int p = ar[i];
        int pos = atomicAdd(&hcur[p >> 17], 1);
        sorted[pos] = p;
    }
    __syncthreads();

    // gather: wave wv handles 8 nodes of quarter q
    const int nodeBase = (b << BSHIFT) + q * 32 + wv * 8;
    for (int r = 0; r < 8; ++r) {
        int node = nodeBase + r;
        if (node >= nnodes) break;
        int dl = node & (GNODES - 1);
        int s0 = hoff[dl];
        int s1 = hoff[dl + 1];
        int m = s1 - s0;

        float4 acc = make_float4(0.f, 0.f, 0.f, 0.f);
        int j = 0;
        for (; j + 16 <= m; j += 16) {
            // 8 edges per half-wave, all loads independent -> deep MLP
            int e0 = sorted[s0 + j + h] & 0x1FFFF;
            int e1 = sorted[s0 + j + 2 + h] & 0x1FFFF;
            int e2 = sorted[s0 + j + 4 + h] & 0x1FFFF;
            int e3 = sorted[s0 + j + 6 + h] & 0x1FFFF;
            int e4 = sorted[s0 + j + 8 + h] & 0x1FFFF;
            int e5 = sorted[s0 + j + 10 + h] & 0x1FFFF;
            int e6 = sorted[s0 + j + 12 + h] & 0x1FFFF;
            int e7 = sorted[s0 + j + 14 + h] & 0x1FFFF;
            ushort4 v0 = xh4[(size_t)e0 * 32 + c];
            ushort4 v1 = xh4[(size_t)e1 * 32 + c];
            ushort4 v2 = xh4[(size_t)e2 * 32 + c];
            ushort4 v3 = xh4[(size_t)e3 * 32 + c];
            ushort4 v4 = xh4[(size_t)e4 * 32 + c];
            ushort4 v5 = xh4[(size_t)e5 * 32 + c];
            ushort4 v6 = xh4[(size_t)e6 * 32 + c];
            ushort4 v7 = xh4[(size_t)e7 * 32 + c];
            acc.x += ((bf2f(v0.x) + bf2f(v1.x)) + (bf2f(v2.x) + bf2f(v3.x))) +
                     ((bf2f(v4.x) + bf2f(v5.x)) + (bf2f(v6.x) + bf2f(v7.x)));
            acc.y += ((bf2f(v0.y) + bf2f(v1.y)) + (bf2f(v2.y) + bf2f(v3.y))) +
                     ((bf2f(v4.y) + bf2f(v5.y)) + (bf2f(v6.y) + bf2f(v7.y)));
            acc.z += ((bf2f(v0.z) + bf2f(v1.z)) + (bf2f(v2.z) + bf2f(v3.z))) +
                     ((bf2f(v4.z) + bf2f(v5.z)) + (bf2f(v6.z) + bf2f(v7.z)));
            acc.w += ((bf2f(v0.w) + bf2f(v1.w)) + (bf2f(v2.w) + bf2f(v3.w))) +
                     ((bf2f(v4.w) + bf2f(v5.w)) + (bf2f(v6.w) + bf2f(v7.w)));
        }
        for (; j < m; j += 2) {
            int e = j + h;
            if (e < m) {
                int p = sorted[s0 + e] & 0x1FFFF;
                ushort4 v = xh4[(size_t)p * 32 + c];
                acc.x += bf2f(v.x);
                acc.y += bf2f(v.y);
                acc.z += bf2f(v.z);
                acc.w += bf2f(v.w);
            }
        }

        acc.x += __shfl_xor(acc.x, 32);
        acc.y += __shfl_xor(acc.y, 32);
        acc.z += __shfl_xor(acc.z, 32);
        acc.w += __shfl_xor(acc.w, 32);

        if (h == 0) {
            float4 xv = x4[(size_t)node * 32 + c];   // exact f32 residual
            out4[(size_t)node * 32 + c] =
                make_float4(xv.x + acc.x, xv.y + acc.y, xv.z + acc.z, xv.w + acc.w);
        }
    }
}

// handles arena-overflow edges (expected none on this data)
__global__ void hgnn_spill_apply(const float4* __restrict__ x4,
                                 const int* __restrict__ spillCnt,
                                 const int2* __restrict__ spill,
                                 float* __restrict__ out, int spillCap) {
    int n = *spillCnt;
    if (n > spillCap) n = spillCap;
    int i = blockIdx.x * blockDim.x + threadIdx.x;
    int stride = gridDim.x * blockDim.x;
    for (int k = i; k < n * 32; k += stride) {
        int e = k >> 5;
        int cc = k & 31;
        int2 sd = spill[e];
        float4 v = x4[(size_t)sd.x * 32 + cc];
        float* o = out + (size_t)sd.y * DIM + cc * 4;
        atomicAdd(o + 0, v.x);
        atomicAdd(o + 1, v.y);
        atomicAdd(o + 2, v.z);
        atomicAdd(o + 3, v.w);
    }
}

static inline size_t align256(size_t v) { return (v + 255) & ~(size_t)255; }

extern "C" void kernel_launch(void* const* d_in, const int* in_sizes, int n_in,
                              void* d_out, int out_size, void* d_ws, size_t ws_size,
                              hipStream_t stream) {
    const float* x = (const float*)d_in[0];
    const int* src = (const int*)d_in[1];
    const int* dst = (const int*)d_in[2];
    float* out = (float*)d_out;

    const int E = in_sizes[1];                   // 2,000,000
    const int N = in_sizes[0] / DIM;             // 100,000
    const int n4 = N * (DIM / 4);                // 3.2M float4
    const int NBK = (N + GNODES - 1) >> BSHIFT;  // 782

    // workspace: cursor[MAXB]+spillCnt | xh bf16 | arena | spill
    char* w = (char*)d_ws;
    size_t curBytes = align256((size_t)(MAXB + 1) * sizeof(int));
    size_t xhBytes = align256((size_t)N * DIM * 2);   // 25.6 MB
    size_t fixedBytes = curBytes + xhBytes;
    size_t spillReserve = 256 * 1024;

    size_t avail = (ws_size > fixedBytes + spillReserve)
                       ? (ws_size - fixedBytes - spillReserve) : 0;
    int cap = (int)((avail / sizeof(int)) / (size_t)NBK);
    if (cap > CAP_MAX) cap = CAP_MAX;
    if (cap < 64) cap = 64;    // degenerate ws; spill net keeps correctness

    int* cursor = (int*)w;                        // [NBK]
    int* spillCnt = cursor + MAXB;                // [1]
    ushort* xh = (ushort*)(w + curBytes);         // [N*128] bf16
    int* arena = (int*)(w + fixedBytes);          // [NBK*cap]
    size_t arenaBytes = align256((size_t)NBK * cap * sizeof(int));
    int2* spill = (int2*)(w + fixedBytes + arenaBytes);
    int spillCap = (int)((ws_size > fixedBytes + arenaBytes)
                             ? (ws_size - fixedBytes - arenaBytes) / sizeof(int2)
                             : 0);

    // 1) zero bucket cursors + spill counter
    hipMemsetAsync(cursor, 0, (size_t)(MAXB + 1) * sizeof(int), stream);

    // 2) x -> bf16 mirror
    hipLaunchKernelGGL(hgnn_convert, dim3(2048), dim3(256), 0, stream,
                       (const float4*)x, (ushort4*)xh, n4);

    // 3) clustered reservation partition into per-bucket arenas
    hipLaunchKernelGGL(hgnn_partition_arena, dim3((E + CE - 1) / CE), dim3(256),
                       0, stream, src, dst, cursor, arena, cap,
                       spillCnt, spill, spillCap, E, NBK);

    // 4) fused sort + gather-aggregate (4 blocks per bucket)
    hipLaunchKernelGGL(hgnn_aggregate_sorted, dim3(NBK * 4), dim3(256), 0, stream,
                       (const float4*)x, (const ushort4*)xh, arena, cap,
                       cursor, (float4*)out, N);

    // 5) apply spilled edges (normally zero work)
    hipLaunchKernelGGL(hgnn_spill_apply, dim3(64), dim3(256), 0, stream,
                       (const float4*)x, spillCnt, spill, out, spillCap);
}

// Round 9
// 141.074 us; speedup vs baseline: 2.0246x; 1.0820x over previous
//
#include <hip/hip_runtime.h>

// HGNN aggregation: out = x + segment_sum(x[src_idx], dst_idx)
// x: [100000, 128] f32; src_idx/dst_idx: [2,000,000] int32.
//
// Round 9: fused convert∥partition + quarter-filtered sort + predicated gather.
//   1. memset bucket cursors (+ spill counter)
//   2. convert_partition (ONE kernel): blocks [0,nPart) do the clustered
//      reservation partition into per-bucket arenas; blocks [nPart,grid) do
//      x -> bf16 mirror (+ zero pad row N) concurrently.
//   3. aggregate_sorted: 4 blocks per bucket; each block counting-sorts ONLY
//      its 32-node quarter (32-bin LDS hist), then 4 waves x 8 nodes gather
//      bf16 rows with zero-row predication (no tail loop, 8-deep MLP per
//      half-wave), f32 accum + exact f32 residual.
//   4. spill_apply: f32 atomics for arena/quarter overflow (expected 0).

constexpr int DIM = 128;
constexpr int BSHIFT = 7;            // 128 nodes per bucket
constexpr int GNODES = 1 << BSHIFT;  // 128
constexpr int MAXB = 1024;           // max buckets (N <= 131072)
constexpr int CE = 8192;             // edges per partition block
constexpr int CAP_MAX = 3072;        // arena slots per bucket
constexpr int QCAP = 1536;           // per-quarter sorted capacity (mean 640)

__device__ inline unsigned short f2bf(float f) {
    unsigned u = __float_as_uint(f);
    u = (u + 0x7FFFu + ((u >> 16) & 1u)) >> 16;   // RTNE
    return (unsigned short)u;
}
__device__ inline float bf2f(unsigned short h) {
    return __uint_as_float((unsigned)h << 16);
}

__global__ void hgnn_convert_partition(const float4* __restrict__ x4,
                                       ushort4* __restrict__ xh4, int n4,
                                       const int* __restrict__ src,
                                       const int* __restrict__ dst,
                                       int* __restrict__ cursor,
                                       int* __restrict__ arena, int cap,
                                       int* __restrict__ spillCnt,
                                       int2* __restrict__ spill, int spillCap,
                                       int nedges, int nbk, int nPart) {
    __shared__ int h[MAXB];
    __shared__ int lb[MAXB];
    const int tid = threadIdx.x;

    if ((int)blockIdx.x < nPart) {
        // ---- partition path ----
        int c0 = blockIdx.x * CE;
        int c1 = min(c0 + CE, nedges);
        for (int i = tid; i < nbk; i += blockDim.x) h[i] = 0;
        __syncthreads();
        for (int i = c0 + tid; i < c1; i += blockDim.x)
            atomicAdd(&h[dst[i] >> BSHIFT], 1);
        __syncthreads();
        for (int i = tid; i < nbk; i += blockDim.x)
            lb[i] = h[i] ? atomicAdd(&cursor[i], h[i]) : 0;
        __syncthreads();
        for (int i = c0 + tid; i < c1; i += blockDim.x) {
            int s = src[i];
            int d = dst[i];
            int bk = d >> BSHIFT;
            int pos = atomicAdd(&lb[bk], 1);
            if (pos < cap) {
                arena[(size_t)bk * cap + pos] = s | ((d & (GNODES - 1)) << 17);
            } else {
                int sp = atomicAdd(spillCnt, 1);
                if (sp < spillCap) spill[sp] = make_int2(s, d);
            }
        }
    } else {
        // ---- convert path (concurrent with partition) ----
        int bid = blockIdx.x - nPart;
        int nconv = gridDim.x - nPart;
        int i = bid * blockDim.x + tid;
        int stride = nconv * blockDim.x;
        for (int k = i; k < n4; k += stride) {
            float4 v = x4[k];
            ushort4 o;
            o.x = f2bf(v.x); o.y = f2bf(v.y);
            o.z = f2bf(v.z); o.w = f2bf(v.w);
            xh4[k] = o;
        }
        // zero pad row (row index N) for predicated gather
        if (bid == 0 && tid < DIM / 4) {
            ushort4 z; z.x = 0; z.y = 0; z.z = 0; z.w = 0;
            xh4[n4 + tid] = z;
        }
    }
}

// 4 blocks per bucket; block q sorts ONLY quarter q (nodes q*32..q*32+31).
__global__ void hgnn_aggregate_sorted(const float4* __restrict__ x4,
                                      const ushort4* __restrict__ xh4,
                                      const int* __restrict__ arena, int cap,
                                      const int* __restrict__ cursor,
                                      float4* __restrict__ out4, int nnodes,
                                      int* __restrict__ spillCnt,
                                      int2* __restrict__ spill, int spillCap) {
    __shared__ int qsorted[QCAP];
    __shared__ int hoff[33];
    __shared__ int hcur[32];

    const int b = blockIdx.x >> 2;
    const int q = blockIdx.x & 3;
    const int tid = threadIdx.x;
    const int wv = tid >> 6;
    const int lane = tid & 63;
    const int h = lane >> 5;
    const int c = lane & 31;
    const int ZROW = nnodes;          // zeros row in xh

    int cnt = cursor[b];
    if (cnt > cap) cnt = cap;
    const int* ar = arena + (size_t)b * cap;

    // pass 1: 32-bin histogram over this quarter's edges
    if (tid < 32) hcur[tid] = 0;
    __syncthreads();
    for (int i = tid; i < cnt; i += blockDim.x) {
        int dl = ar[i] >> 17;
        if ((dl >> 5) == q) atomicAdd(&hcur[dl & 31], 1);
    }
    __syncthreads();

    // inclusive scan of 32 counts into hoff[1..32], hoff[0]=0
    int myc = (tid < 32) ? hcur[tid] : 0;
    if (tid < 32) hoff[tid + 1] = myc;
    if (tid == 0) hoff[0] = 0;
    __syncthreads();
    for (int off = 1; off < 32; off <<= 1) {
        int v = (tid < 32 && tid >= off) ? hoff[tid + 1 - off] : 0;
        __syncthreads();
        if (tid < 32) hoff[tid + 1] += v;
        __syncthreads();
    }
    if (tid < 32) hcur[tid] = hoff[tid];   // exclusive offsets -> cursors
    __syncthreads();

    // pass 2: scatter this quarter's edges into sorted LDS list
    for (int i = tid; i < cnt; i += blockDim.x) {
        int p = ar[i];
        int dl = p >> 17;
        if ((dl >> 5) == q) {
            int pos = atomicAdd(&hcur[dl & 31], 1);
            if (pos < QCAP) {
                qsorted[pos] = p;
            } else {                       // pathological skew only
                int sp = atomicAdd(spillCnt, 1);
                if (sp < spillCap)
                    spill[sp] = make_int2(p & 0x1FFFF, (b << BSHIFT) + dl);
            }
        }
    }
    __syncthreads();

    // gather: wave wv handles 8 nodes of this quarter; zero-row predication
    const int nodeBase = (b << BSHIFT) + q * 32 + wv * 8;
    for (int r = 0; r < 8; ++r) {
        int node = nodeBase + r;
        if (node >= nnodes) break;
        int bin = node & 31;
        int s0 = hoff[bin];
        int m = hoff[bin + 1] - s0;
        if (m > QCAP - s0) m = QCAP - s0;   // clamp vs overflow-spilled

        float4 acc = make_float4(0.f, 0.f, 0.f, 0.f);
        for (int j = 0; j < m; j += 16) {
#pragma unroll
            for (int k = 0; k < 8; ++k) {
                int e = j + 2 * k + h;
                bool ok = e < m;
                int p = ok ? (qsorted[s0 + e] & 0x1FFFF) : ZROW;
                ushort4 v = xh4[(size_t)p * 32 + c];
                acc.x += bf2f(v.x);
                acc.y += bf2f(v.y);
                acc.z += bf2f(v.z);
                acc.w += bf2f(v.w);
            }
        }

        acc.x += __shfl_xor(acc.x, 32);
        acc.y += __shfl_xor(acc.y, 32);
        acc.z += __shfl_xor(acc.z, 32);
        acc.w += __shfl_xor(acc.w, 32);

        if (h == 0) {
            float4 xv = x4[(size_t)node * 32 + c];   // exact f32 residual
            out4[(size_t)node * 32 + c] =
                make_float4(xv.x + acc.x, xv.y + acc.y, xv.z + acc.z, xv.w + acc.w);
        }
    }
}

// handles overflow edges (expected none on this data)
__global__ void hgnn_spill_apply(const float4* __restrict__ x4,
                                 const int* __restrict__ spillCnt,
                                 const int2* __restrict__ spill,
                                 float* __restrict__ out, int spillCap) {
    int n = *spillCnt;
    if (n > spillCap) n = spillCap;
    int i = blockIdx.x * blockDim.x + threadIdx.x;
    int stride = gridDim.x * blockDim.x;
    for (int k = i; k < n * 32; k += stride) {
        int e = k >> 5;
        int cc = k & 31;
        int2 sd = spill[e];
        float4 v = x4[(size_t)sd.x * 32 + cc];
        float* o = out + (size_t)sd.y * DIM + cc * 4;
        atomicAdd(o + 0, v.x);
        atomicAdd(o + 1, v.y);
        atomicAdd(o + 2, v.z);
        atomicAdd(o + 3, v.w);
    }
}

static inline size_t align256(size_t v) { return (v + 255) & ~(size_t)255; }

extern "C" void kernel_launch(void* const* d_in, const int* in_sizes, int n_in,
                              void* d_out, int out_size, void* d_ws, size_t ws_size,
                              hipStream_t stream) {
    const float* x = (const float*)d_in[0];
    const int* src = (const int*)d_in[1];
    const int* dst = (const int*)d_in[2];
    float* out = (float*)d_out;

    const int E = in_sizes[1];                   // 2,000,000
    const int N = in_sizes[0] / DIM;             // 100,000
    const int n4 = N * (DIM / 4);                // 3.2M float4
    const int NBK = (N + GNODES - 1) >> BSHIFT;  // 782
    const int nPart = (E + CE - 1) / CE;         // 245 partition blocks

    // workspace: cursor[MAXB]+spillCnt | xh bf16 (N+1 rows) | arena | spill
    char* w = (char*)d_ws;
    size_t curBytes = align256((size_t)(MAXB + 1) * sizeof(int));
    size_t xhBytes = align256((size_t)(N + 1) * DIM * 2);   // +pad row
    size_t fixedBytes = curBytes + xhBytes;
    size_t spillReserve = 256 * 1024;

    size_t avail = (ws_size > fixedBytes + spillReserve)
                       ? (ws_size - fixedBytes - spillReserve) : 0;
    int cap = (int)((avail / sizeof(int)) / (size_t)NBK);
    if (cap > CAP_MAX) cap = CAP_MAX;
    if (cap < 64) cap = 64;    // degenerate ws; spill net keeps correctness

    int* cursor = (int*)w;                        // [NBK]
    int* spillCnt = cursor + MAXB;                // [1]
    ushort* xh = (ushort*)(w + curBytes);         // [(N+1)*128] bf16
    int* arena = (int*)(w + fixedBytes);          // [NBK*cap]
    size_t arenaBytes = align256((size_t)NBK * cap * sizeof(int));
    int2* spill = (int2*)(w + fixedBytes + arenaBytes);
    int spillCap = (int)((ws_size > fixedBytes + arenaBytes)
                             ? (ws_size - fixedBytes - arenaBytes) / sizeof(int2)
                             : 0);

    // 1) zero bucket cursors + spill counter
    hipMemsetAsync(cursor, 0, (size_t)(MAXB + 1) * sizeof(int), stream);

    // 2) fused: partition (blocks 0..nPart) || bf16 convert (the rest)
    {
        int grid = nPart + 1792;
        hipLaunchKernelGGL(hgnn_convert_partition, dim3(grid), dim3(256), 0,
                           stream, (const float4*)x, (ushort4*)xh, n4,
                           src, dst, cursor, arena, cap,
                           spillCnt, spill, spillCap, E, NBK, nPart);
    }

    // 3) fused quarter-sort + gather-aggregate (4 blocks per bucket)
    hipLaunchKernelGGL(hgnn_aggregate_sorted, dim3(NBK * 4), dim3(256), 0, stream,
                       (const float4*)x, (const ushort4*)xh, arena, cap,
                       cursor, (float4*)out, N, spillCnt, spill, spillCap);

    // 4) apply spilled edges (normally zero work)
    hipLaunchKernelGGL(hgnn_spill_apply, dim3(64), dim3(256), 0, stream,
                       (const float4*)x, spillCnt, spill, out, spillCap);
}